// Round 1
// baseline (434.560 us; speedup 1.0000x reference)
//
#include <hip/hip_runtime.h>
#include <math.h>

#define BB 32
#define HH 128
#define SS 8192

typedef __attribute__((ext_vector_type(8))) short bf8;
typedef __attribute__((ext_vector_type(4))) float f4;

static __device__ __forceinline__ unsigned short f2bf(float x) {
  union { float f; unsigned int u; } c; c.f = x;
  unsigned int r = c.u + 0x7FFFu + ((c.u >> 16) & 1u);  // RNE
  return (unsigned short)(r >> 16);
}

// ---------------- prep: bias[b][h] = W[h, 256:384] . dec[b]; Abf = bf16(W[:,0:256]) ----------------
__global__ __launch_bounds__(256) void prep_kernel(
    const float* __restrict__ W, const float* __restrict__ dec,
    unsigned short* __restrict__ Abf, float* __restrict__ bias) {
  const int b = blockIdx.x;
  const int tid = threadIdx.x;
  if (tid < HH) {
    const float* wr = W + (size_t)tid * 384 + 256;
    const float* db = dec + (size_t)b * HH;
    float acc = 0.f;
    #pragma unroll 8
    for (int j = 0; j < HH; ++j) acc += wr[j] * db[j];
    bias[b * HH + tid] = acc;
  }
  if (b == 0) {
    for (int idx = tid; idx < HH * 256; idx += 256) {
      int h = idx >> 8, k = idx & 255;
      Abf[idx] = f2bf(W[h * 384 + k]);
    }
  }
}

// ---------------- main: scores[b][s] = sum_h v[h] * tanh(A@X + bias) ----------------
__global__ __launch_bounds__(256) void attn_main(
    const float* __restrict__ sta, const float* __restrict__ dyn,
    const unsigned short* __restrict__ Abf, const float* __restrict__ bias,
    const float* __restrict__ v, float* __restrict__ scores) {
  __shared__ unsigned short Bl[128 * 130];  // [k][n], row stride 130 elems (conflict-free writes)

  const int tid  = threadIdx.x;
  const int b    = blockIdx.x >> 6;
  const int s0   = (blockIdx.x & 63) << 7;   // 128-wide s tile
  const int w    = tid >> 6;                 // wave id 0..3
  const int l    = tid & 63;
  const int quad = l >> 4;
  const int n16  = l & 15;

  f4 acc[8][2];
  #pragma unroll
  for (int mt = 0; mt < 8; ++mt)
    #pragma unroll
    for (int nt = 0; nt < 2; ++nt) acc[mt][nt] = (f4){0.f, 0.f, 0.f, 0.f};

  for (int c = 0; c < 2; ++c) {  // chunk 0 = static (k 0..127), chunk 1 = dynamic (k 128..255)
    const float* src = (c == 0 ? sta : dyn) + ((size_t)b << 20) + s0;
    __syncthreads();
    // stage 128(k) x 128(n) fp32 -> bf16; coalesced float2 reads, conflict-free dword LDS writes
    #pragma unroll 4
    for (int it = 0; it < 32; ++it) {
      int idx = (it << 8) + tid;          // 0..8191
      int n2  = idx & 63;                 // column pair
      int k   = idx >> 6;                 // 0..127
      const float2 x = *(const float2*)(src + (size_t)k * SS + (n2 << 1));
      unsigned int pk = (unsigned int)f2bf(x.x) | ((unsigned int)f2bf(x.y) << 16);
      *(unsigned int*)&Bl[k * 130 + (n2 << 1)] = pk;
    }
    __syncthreads();

    #pragma unroll
    for (int kk = 0; kk < 4; ++kk) {      // 4 k-steps of 32
      const int k0 = kk << 5;
      // B fragments: B[k=quad*8+j][n]
      bf8 bfr[2];
      #pragma unroll
      for (int nt = 0; nt < 2; ++nt) {
        const int n = (w << 5) + (nt << 4) + n16;
        const unsigned short* bp = &Bl[(k0 + (quad << 3)) * 130 + n];
        bf8 t;
        #pragma unroll
        for (int j = 0; j < 8; ++j) t[j] = (short)bp[j * 130];
        bfr[nt] = t;
      }
      // A fragments straight from global (64KB, L2-resident): A[m=lane&15][k=quad*8+j]
      #pragma unroll
      for (int mt = 0; mt < 8; ++mt) {
        const unsigned short* ap =
            Abf + (((size_t)(mt * 16 + n16)) << 8) + (c << 7) + k0 + (quad << 3);
        bf8 af = *(const bf8*)ap;  // 16B aligned
        #pragma unroll
        for (int nt = 0; nt < 2; ++nt)
          acc[mt][nt] = __builtin_amdgcn_mfma_f32_16x16x32_bf16(af, bfr[nt], acc[mt][nt], 0, 0, 0);
      }
    }
  }

  // epilogue: z = acc + bias[h]; part += v[h]*tanh(z); reduce over h (rows) across quads
  float part[2] = {0.f, 0.f};
  #pragma unroll
  for (int mt = 0; mt < 8; ++mt) {
    #pragma unroll
    for (int r = 0; r < 4; ++r) {
      const int h = mt * 16 + quad * 4 + r;   // C/D row = quad*4 + reg
      const float bv = bias[(b << 7) + h];
      const float vv = v[h];
      #pragma unroll
      for (int nt = 0; nt < 2; ++nt) {
        float z = acc[mt][nt][r] + bv;
        part[nt] += vv * tanhf(z);
      }
    }
  }
  #pragma unroll
  for (int nt = 0; nt < 2; ++nt) {
    float p = part[nt];
    p += __shfl_xor(p, 16, 64);
    p += __shfl_xor(p, 32, 64);
    if (quad == 0)
      scores[((size_t)b << 13) + s0 + (w << 5) + (nt << 4) + n16] = p;
  }
}

// ---------------- softmax over s, in-place on d_out ----------------
__global__ __launch_bounds__(1024) void softmax_kernel(float* __restrict__ out) {
  const int b = blockIdx.x;
  const int tid = threadIdx.x;
  float* row = out + ((size_t)b << 13);
  float4 x0 = ((const float4*)row)[tid];
  float4 x1 = ((const float4*)row)[tid + 1024];
  float lmax = fmaxf(fmaxf(fmaxf(x0.x, x0.y), fmaxf(x0.z, x0.w)),
                     fmaxf(fmaxf(x1.x, x1.y), fmaxf(x1.z, x1.w)));
  __shared__ float red[17];
  #pragma unroll
  for (int o = 32; o >= 1; o >>= 1) lmax = fmaxf(lmax, __shfl_xor(lmax, o, 64));
  if ((tid & 63) == 0) red[tid >> 6] = lmax;
  __syncthreads();
  if (tid < 64) {
    float m = (tid < 16) ? red[tid] : -3.0e38f;
    #pragma unroll
    for (int o = 8; o >= 1; o >>= 1) m = fmaxf(m, __shfl_xor(m, o, 64));
    if (tid == 0) red[16] = m;
  }
  __syncthreads();
  const float gmax = red[16];
  float e[8];
  e[0] = expf(x0.x - gmax); e[1] = expf(x0.y - gmax);
  e[2] = expf(x0.z - gmax); e[3] = expf(x0.w - gmax);
  e[4] = expf(x1.x - gmax); e[5] = expf(x1.y - gmax);
  e[6] = expf(x1.z - gmax); e[7] = expf(x1.w - gmax);
  float ls = e[0] + e[1] + e[2] + e[3] + e[4] + e[5] + e[6] + e[7];
  #pragma unroll
  for (int o = 32; o >= 1; o >>= 1) ls += __shfl_xor(ls, o, 64);
  __syncthreads();   // gmax consumed; safe to reuse red
  if ((tid & 63) == 0) red[tid >> 6] = ls;
  __syncthreads();
  if (tid < 64) {
    float m = (tid < 16) ? red[tid] : 0.f;
    #pragma unroll
    for (int o = 8; o >= 1; o >>= 1) m += __shfl_xor(m, o, 64);
    if (tid == 0) red[16] = m;
  }
  __syncthreads();
  const float inv = 1.0f / red[16];
  float4 o0 = make_float4(e[0] * inv, e[1] * inv, e[2] * inv, e[3] * inv);
  float4 o1 = make_float4(e[4] * inv, e[5] * inv, e[6] * inv, e[7] * inv);
  ((float4*)row)[tid] = o0;
  ((float4*)row)[tid + 1024] = o1;
}

extern "C" void kernel_launch(void* const* d_in, const int* in_sizes, int n_in,
                              void* d_out, int out_size, void* d_ws, size_t ws_size,
                              hipStream_t stream) {
  const float* sta = (const float*)d_in[0];   // (32,128,8192)
  const float* dyn = (const float*)d_in[1];   // (32,128,8192)
  const float* dec = (const float*)d_in[2];   // (32,128)
  const float* v   = (const float*)d_in[3];   // (128)
  const float* W   = (const float*)d_in[4];   // (128,384)

  unsigned short* Abf = (unsigned short*)d_ws;             // 64 KB
  float* bias = (float*)((char*)d_ws + 128 * 256 * 2);     // 16 KB
  float* scores = (float*)d_out;                           // 1 MB, softmaxed in place

  prep_kernel<<<BB, 256, 0, stream>>>(W, dec, Abf, bias);
  attn_main<<<BB * (SS / 128), 256, 0, stream>>>(sta, dyn, Abf, bias, v, scores);
  softmax_kernel<<<BB, 1024, 0, stream>>>(scores);
}

// Round 2
// 386.600 us; speedup vs baseline: 1.1241x; 1.1241x over previous
//
#include <hip/hip_runtime.h>
#include <math.h>

#define BB 32
#define HH 128
#define SS 8192

typedef __attribute__((ext_vector_type(8))) short bf8;
typedef __attribute__((ext_vector_type(4))) float f4;

static __device__ __forceinline__ unsigned short f2bf(float x) {
  union { float f; unsigned int u; } c; c.f = x;
  unsigned int r = c.u + 0x7FFFu + ((c.u >> 16) & 1u);  // RNE
  return (unsigned short)(r >> 16);
}

// ---------------- prep: bias[b][h] = W[h, 256:384] . dec[b]; Abf = bf16(W[:,0:256]) ----------------
__global__ __launch_bounds__(256) void prep_kernel(
    const float* __restrict__ W, const float* __restrict__ dec,
    unsigned short* __restrict__ Abf, float* __restrict__ bias) {
  const int b = blockIdx.x;
  const int tid = threadIdx.x;
  if (tid < HH) {
    const float* wr = W + (size_t)tid * 384 + 256;
    const float* db = dec + (size_t)b * HH;
    float acc = 0.f;
    #pragma unroll 8
    for (int j = 0; j < HH; ++j) acc += wr[j] * db[j];
    bias[b * HH + tid] = acc;
  }
  if (b == 0) {
    for (int idx = tid; idx < HH * 256; idx += 256) {
      int h = idx >> 8, k = idx & 255;
      Abf[idx] = f2bf(W[h * 384 + k]);
    }
  }
}

// ---------------- main: scores[b][s] = sum_h v[h] * tanh(A@X + bias) ----------------
// One wave per block; wave owns a 32-wide s strip, m=128 (8 mt tiles), k=256 (8 steps of 32).
// B fragments stream straight from global (no LDS, no barriers); fp32 held in regs,
// converted to bf16 at use; one-step software prefetch.
__global__ __launch_bounds__(64) void attn_main(
    const float* __restrict__ sta, const float* __restrict__ dyn,
    const unsigned short* __restrict__ Abf, const float* __restrict__ bias,
    const float* __restrict__ v, float* __restrict__ scores) {
  const int l    = threadIdx.x;
  const int b    = blockIdx.x >> 8;
  const int tile = blockIdx.x & 255;       // 256 tiles of 32 columns
  const int quad = l >> 4;
  const int n16  = l & 15;
  const int col0 = (tile << 5) + n16;      // + nt*16

  const size_t base = ((size_t)b << 20) + ((size_t)(quad << 3)) * SS;
  const float* p0 = sta + base;            // rows quad*8.., chunk 0 (k 0..127)
  const float* p1 = dyn + base;            // chunk 1 (k 128..255)

  f4 acc[8][2];
  #pragma unroll
  for (int mt = 0; mt < 8; ++mt) {
    acc[mt][0] = (f4){0.f, 0.f, 0.f, 0.f};
    acc[mt][1] = (f4){0.f, 0.f, 0.f, 0.f};
  }

  float bcur[2][8], bnxt[2][8];

  auto loadB = [&](int step, float (&dst)[2][8]) {
    const float* tp = (step < 4 ? p0 : p1) + ((size_t)((step & 3) << 5)) * SS;
    #pragma unroll
    for (int nt = 0; nt < 2; ++nt) {
      const float* p = tp + col0 + (nt << 4);
      #pragma unroll
      for (int j = 0; j < 8; ++j)
        dst[nt][j] = p[(size_t)j * SS];   // 4 rows x 64B segments per instr, fully coalesced
    }
  };

  loadB(0, bcur);
  #pragma unroll
  for (int step = 0; step < 8; ++step) {
    if (step < 7) loadB(step + 1, bnxt);
    // convert current step to bf16 fragments
    bf8 bfr[2];
    #pragma unroll
    for (int nt = 0; nt < 2; ++nt) {
      bf8 t;
      #pragma unroll
      for (int j = 0; j < 8; ++j) t[j] = (short)f2bf(bcur[nt][j]);
      bfr[nt] = t;
    }
    // A fragments from L2-resident 64KB bf16 copy: A[m=lane&15][k=quad*8+j]
    const unsigned short* abase = Abf + ((size_t)n16 << 8) + (step << 5) + (quad << 3);
    #pragma unroll
    for (int mt = 0; mt < 8; ++mt) {
      bf8 af = *(const bf8*)(abase + (mt << 12));  // (mt*16)*256 elems
      acc[mt][0] = __builtin_amdgcn_mfma_f32_16x16x32_bf16(af, bfr[0], acc[mt][0], 0, 0, 0);
      acc[mt][1] = __builtin_amdgcn_mfma_f32_16x16x32_bf16(af, bfr[1], acc[mt][1], 0, 0, 0);
    }
    if (step < 7) {
      #pragma unroll
      for (int nt = 0; nt < 2; ++nt)
        #pragma unroll
        for (int j = 0; j < 8; ++j) bcur[nt][j] = bnxt[nt][j];
    }
  }

  // epilogue: z = acc + bias[h]; part += v[h]*tanh(z); reduce over h (rows) across quads
  float part[2] = {0.f, 0.f};
  #pragma unroll
  for (int mt = 0; mt < 8; ++mt) {
    #pragma unroll
    for (int r = 0; r < 4; ++r) {
      const int h = mt * 16 + quad * 4 + r;   // C/D row = quad*4 + reg
      const float bv = bias[(b << 7) + h];
      const float vv = v[h];
      #pragma unroll
      for (int nt = 0; nt < 2; ++nt) {
        float z = acc[mt][nt][r] + bv;
        part[nt] += vv * tanhf(z);
      }
    }
  }
  #pragma unroll
  for (int nt = 0; nt < 2; ++nt) {
    float p = part[nt];
    p += __shfl_xor(p, 16, 64);
    p += __shfl_xor(p, 32, 64);
    if (quad == 0)
      scores[((size_t)b << 13) + (tile << 5) + (nt << 4) + n16] = p;
  }
}

// ---------------- softmax over s, in-place on d_out ----------------
__global__ __launch_bounds__(1024) void softmax_kernel(float* __restrict__ out) {
  const int b = blockIdx.x;
  const int tid = threadIdx.x;
  float* row = out + ((size_t)b << 13);
  float4 x0 = ((const float4*)row)[tid];
  float4 x1 = ((const float4*)row)[tid + 1024];
  float lmax = fmaxf(fmaxf(fmaxf(x0.x, x0.y), fmaxf(x0.z, x0.w)),
                     fmaxf(fmaxf(x1.x, x1.y), fmaxf(x1.z, x1.w)));
  __shared__ float red[17];
  #pragma unroll
  for (int o = 32; o >= 1; o >>= 1) lmax = fmaxf(lmax, __shfl_xor(lmax, o, 64));
  if ((tid & 63) == 0) red[tid >> 6] = lmax;
  __syncthreads();
  if (tid < 64) {
    float m = (tid < 16) ? red[tid] : -3.0e38f;
    #pragma unroll
    for (int o = 8; o >= 1; o >>= 1) m = fmaxf(m, __shfl_xor(m, o, 64));
    if (tid == 0) red[16] = m;
  }
  __syncthreads();
  const float gmax = red[16];
  float e[8];
  e[0] = expf(x0.x - gmax); e[1] = expf(x0.y - gmax);
  e[2] = expf(x0.z - gmax); e[3] = expf(x0.w - gmax);
  e[4] = expf(x1.x - gmax); e[5] = expf(x1.y - gmax);
  e[6] = expf(x1.z - gmax); e[7] = expf(x1.w - gmax);
  float ls = e[0] + e[1] + e[2] + e[3] + e[4] + e[5] + e[6] + e[7];
  #pragma unroll
  for (int o = 32; o >= 1; o >>= 1) ls += __shfl_xor(ls, o, 64);
  __syncthreads();   // gmax consumed; safe to reuse red
  if ((tid & 63) == 0) red[tid >> 6] = ls;
  __syncthreads();
  if (tid < 64) {
    float m = (tid < 16) ? red[tid] : 0.f;
    #pragma unroll
    for (int o = 8; o >= 1; o >>= 1) m += __shfl_xor(m, o, 64);
    if (tid == 0) red[16] = m;
  }
  __syncthreads();
  const float inv = 1.0f / red[16];
  float4 o0 = make_float4(e[0] * inv, e[1] * inv, e[2] * inv, e[3] * inv);
  float4 o1 = make_float4(e[4] * inv, e[5] * inv, e[6] * inv, e[7] * inv);
  ((float4*)row)[tid] = o0;
  ((float4*)row)[tid + 1024] = o1;
}

extern "C" void kernel_launch(void* const* d_in, const int* in_sizes, int n_in,
                              void* d_out, int out_size, void* d_ws, size_t ws_size,
                              hipStream_t stream) {
  const float* sta = (const float*)d_in[0];   // (32,128,8192)
  const float* dyn = (const float*)d_in[1];   // (32,128,8192)
  const float* dec = (const float*)d_in[2];   // (32,128)
  const float* v   = (const float*)d_in[3];   // (128)
  const float* W   = (const float*)d_in[4];   // (128,384)

  unsigned short* Abf = (unsigned short*)d_ws;             // 64 KB
  float* bias = (float*)((char*)d_ws + 128 * 256 * 2);     // 16 KB
  float* scores = (float*)d_out;                           // 1 MB, softmaxed in place

  prep_kernel<<<BB, 256, 0, stream>>>(W, dec, Abf, bias);
  attn_main<<<BB * (SS / 32), 64, 0, stream>>>(sta, dyn, Abf, bias, v, scores);
  softmax_kernel<<<BB, 1024, 0, stream>>>(scores);
}

// Round 3
// 378.764 us; speedup vs baseline: 1.1473x; 1.0207x over previous
//
#include <hip/hip_runtime.h>
#include <math.h>

#define BB 32
#define HH 128
#define SS 8192

typedef __attribute__((ext_vector_type(8))) short bf8;
typedef __attribute__((ext_vector_type(4))) float f4;

static __device__ __forceinline__ unsigned short f2bf(float x) {
  union { float f; unsigned int u; } c; c.f = x;
  unsigned int r = c.u + 0x7FFFu + ((c.u >> 16) & 1u);  // RNE
  return (unsigned short)(r >> 16);
}

// ---------------- prep: bias[b][h] = W[h, 256:384] . dec[b]; Abf = bf16(W[:,0:256]) ----------------
__global__ __launch_bounds__(256) void prep_kernel(
    const float* __restrict__ W, const float* __restrict__ dec,
    unsigned short* __restrict__ Abf, float* __restrict__ bias) {
  const int b = blockIdx.x;
  const int tid = threadIdx.x;
  if (tid < HH) {
    const float* wr = W + (size_t)tid * 384 + 256;
    const float* db = dec + (size_t)b * HH;
    float acc = 0.f;
    #pragma unroll 8
    for (int j = 0; j < HH; ++j) acc += wr[j] * db[j];
    bias[b * HH + tid] = acc;
  }
  if (b == 0) {
    for (int idx = tid; idx < HH * 256; idx += 256) {
      int h = idx >> 8, k = idx & 255;
      Abf[idx] = f2bf(W[h * 384 + k]);
    }
  }
}

// ---------------- main: scores[b][s] = sum_h v[h] * tanh(A@X + bias) ----------------
// 4 independent waves per 256-thread block (no LDS, no syncs). Each wave owns a
// 32-wide s strip; its two 16-col MFMA n-tiles are the EVEN and ODD columns of the
// strip, so each lane's B data for both tiles is one contiguous float2 -> every
// global_load_dwordx2 covers full 128B L2 lines (16 lanes x 8B per row, 4 rows).
// One-step software prefetch; fp32 in regs, bf16 convert at use.
__global__ __launch_bounds__(256, 4) void attn_main(
    const float* __restrict__ sta, const float* __restrict__ dyn,
    const unsigned short* __restrict__ Abf, const float* __restrict__ bias,
    const float* __restrict__ v, float* __restrict__ scores) {
  const int tid  = threadIdx.x;
  const int l    = tid & 63;
  const int gw   = (blockIdx.x << 2) + (tid >> 6);  // global wave id
  const int b    = gw >> 8;
  const int tile = gw & 255;                        // 256 tiles of 32 columns
  const int quad = l >> 4;
  const int n16  = l & 15;
  const int s0   = tile << 5;

  const size_t base = ((size_t)b << 20) + (size_t)(quad << 3) * SS + s0 + (n16 << 1);
  const float* p0 = sta + base;            // rows quad*8.., chunk 0 (k 0..127)
  const float* p1 = dyn + base;            // chunk 1 (k 128..255)

  f4 acc[8][2];
  #pragma unroll
  for (int mt = 0; mt < 8; ++mt) {
    acc[mt][0] = (f4){0.f, 0.f, 0.f, 0.f};
    acc[mt][1] = (f4){0.f, 0.f, 0.f, 0.f};
  }

  float2 bcur[8], bnxt[8];

  auto loadB = [&](int step, float2 (&dst)[8]) {
    const float* tp = (step < 4 ? p0 : p1) + ((size_t)((step & 3) << 5)) * SS;
    #pragma unroll
    for (int j = 0; j < 8; ++j)
      dst[j] = *(const float2*)(tp + (size_t)j * SS);  // 128B full-line segments
  };

  loadB(0, bcur);
  #pragma unroll
  for (int step = 0; step < 8; ++step) {
    if (step < 7) loadB(step + 1, bnxt);
    // current step -> bf16 fragments: tile0 = even cols (.x), tile1 = odd cols (.y)
    bf8 bfr0, bfr1;
    #pragma unroll
    for (int j = 0; j < 8; ++j) {
      bfr0[j] = (short)f2bf(bcur[j].x);
      bfr1[j] = (short)f2bf(bcur[j].y);
    }
    // A fragments from L2-resident 64KB bf16 copy: A[m=lane&15][k=quad*8+j]
    const unsigned short* abase = Abf + ((size_t)n16 << 8) + (step << 5) + (quad << 3);
    #pragma unroll
    for (int mt = 0; mt < 8; ++mt) {
      bf8 af = *(const bf8*)(abase + (mt << 12));  // (mt*16)*256 elems, 16B aligned
      acc[mt][0] = __builtin_amdgcn_mfma_f32_16x16x32_bf16(af, bfr0, acc[mt][0], 0, 0, 0);
      acc[mt][1] = __builtin_amdgcn_mfma_f32_16x16x32_bf16(af, bfr1, acc[mt][1], 0, 0, 0);
    }
    if (step < 7) {
      #pragma unroll
      for (int j = 0; j < 8; ++j) bcur[j] = bnxt[j];
    }
  }

  // epilogue: z = acc + bias[h]; part += v[h]*tanh(z); reduce over h (rows) across quads
  float part[2] = {0.f, 0.f};
  #pragma unroll
  for (int mt = 0; mt < 8; ++mt) {
    #pragma unroll
    for (int r = 0; r < 4; ++r) {
      const int h = mt * 16 + quad * 4 + r;   // C/D row = quad*4 + reg
      const float bv = bias[(b << 7) + h];
      const float vv = v[h];
      part[0] += vv * tanhf(acc[mt][0][r] + bv);
      part[1] += vv * tanhf(acc[mt][1][r] + bv);
    }
  }
  part[0] += __shfl_xor(part[0], 16, 64);
  part[0] += __shfl_xor(part[0], 32, 64);
  part[1] += __shfl_xor(part[1], 16, 64);
  part[1] += __shfl_xor(part[1], 32, 64);
  if (quad == 0) {
    // tile0 col n16 -> s = s0+2*n16 (even), tile1 -> s0+2*n16+1 (odd): one float2
    float2 o = make_float2(part[0], part[1]);
    *(float2*)(scores + ((size_t)b << 13) + s0 + (n16 << 1)) = o;
  }
}

// ---------------- softmax over s, in-place on d_out ----------------
__global__ __launch_bounds__(1024) void softmax_kernel(float* __restrict__ out) {
  const int b = blockIdx.x;
  const int tid = threadIdx.x;
  float* row = out + ((size_t)b << 13);
  float4 x0 = ((const float4*)row)[tid];
  float4 x1 = ((const float4*)row)[tid + 1024];
  float lmax = fmaxf(fmaxf(fmaxf(x0.x, x0.y), fmaxf(x0.z, x0.w)),
                     fmaxf(fmaxf(x1.x, x1.y), fmaxf(x1.z, x1.w)));
  __shared__ float red[17];
  #pragma unroll
  for (int o = 32; o >= 1; o >>= 1) lmax = fmaxf(lmax, __shfl_xor(lmax, o, 64));
  if ((tid & 63) == 0) red[tid >> 6] = lmax;
  __syncthreads();
  if (tid < 64) {
    float m = (tid < 16) ? red[tid] : -3.0e38f;
    #pragma unroll
    for (int o = 8; o >= 1; o >>= 1) m = fmaxf(m, __shfl_xor(m, o, 64));
    if (tid == 0) red[16] = m;
  }
  __syncthreads();
  const float gmax = red[16];
  float e[8];
  e[0] = expf(x0.x - gmax); e[1] = expf(x0.y - gmax);
  e[2] = expf(x0.z - gmax); e[3] = expf(x0.w - gmax);
  e[4] = expf(x1.x - gmax); e[5] = expf(x1.y - gmax);
  e[6] = expf(x1.z - gmax); e[7] = expf(x1.w - gmax);
  float ls = e[0] + e[1] + e[2] + e[3] + e[4] + e[5] + e[6] + e[7];
  #pragma unroll
  for (int o = 32; o >= 1; o >>= 1) ls += __shfl_xor(ls, o, 64);
  __syncthreads();   // gmax consumed; safe to reuse red
  if ((tid & 63) == 0) red[tid >> 6] = ls;
  __syncthreads();
  if (tid < 64) {
    float m = (tid < 16) ? red[tid] : 0.f;
    #pragma unroll
    for (int o = 8; o >= 1; o >>= 1) m += __shfl_xor(m, o, 64);
    if (tid == 0) red[16] = m;
  }
  __syncthreads();
  const float inv = 1.0f / red[16];
  float4 o0 = make_float4(e[0] * inv, e[1] * inv, e[2] * inv, e[3] * inv);
  float4 o1 = make_float4(e[4] * inv, e[5] * inv, e[6] * inv, e[7] * inv);
  ((float4*)row)[tid] = o0;
  ((float4*)row)[tid + 1024] = o1;
}

extern "C" void kernel_launch(void* const* d_in, const int* in_sizes, int n_in,
                              void* d_out, int out_size, void* d_ws, size_t ws_size,
                              hipStream_t stream) {
  const float* sta = (const float*)d_in[0];   // (32,128,8192)
  const float* dyn = (const float*)d_in[1];   // (32,128,8192)
  const float* dec = (const float*)d_in[2];   // (32,128)
  const float* v   = (const float*)d_in[3];   // (128)
  const float* W   = (const float*)d_in[4];   // (128,384)

  unsigned short* Abf = (unsigned short*)d_ws;             // 64 KB
  float* bias = (float*)((char*)d_ws + 128 * 256 * 2);     // 16 KB
  float* scores = (float*)d_out;                           // 1 MB, softmaxed in place

  prep_kernel<<<BB, 256, 0, stream>>>(W, dec, Abf, bias);
  attn_main<<<BB * (SS / 32) / 4, 256, 0, stream>>>(sta, dyn, Abf, bias, v, scores);
  softmax_kernel<<<BB, 1024, 0, stream>>>(scores);
}

// Round 4
// 361.289 us; speedup vs baseline: 1.2028x; 1.0484x over previous
//
#include <hip/hip_runtime.h>
#include <math.h>

#define BB 32
#define HH 128
#define SS 8192

typedef __attribute__((ext_vector_type(8))) short bf8;
typedef __attribute__((ext_vector_type(4))) float f4;
typedef __attribute__((ext_vector_type(2))) float f2v;

static __device__ __forceinline__ unsigned short f2bf(float x) {
  union { float f; unsigned int u; } c; c.f = x;
  unsigned int r = c.u + 0x7FFFu + ((c.u >> 16) & 1u);  // RNE
  return (unsigned short)(r >> 16);
}

// ---------------- prep: bias[b][h] = W[h, 256:384] . dec[b]; Abf = bf16(W[:,0:256]) ----------------
__global__ __launch_bounds__(256) void prep_kernel(
    const float* __restrict__ W, const float* __restrict__ dec,
    unsigned short* __restrict__ Abf, float* __restrict__ bias) {
  const int b = blockIdx.x;
  const int tid = threadIdx.x;
  if (tid < HH) {
    const float* wr = W + (size_t)tid * 384 + 256;
    const float* db = dec + (size_t)b * HH;
    float acc = 0.f;
    #pragma unroll 8
    for (int j = 0; j < HH; ++j) acc += wr[j] * db[j];
    bias[b * HH + tid] = acc;
  }
  if (b == 0) {
    for (int idx = tid; idx < HH * 256; idx += 256) {
      int h = idx >> 8, k = idx & 255;
      Abf[idx] = f2bf(W[h * 384 + k]);
    }
  }
}

// ---------------- main: scores[b][s] = sum_h v[h] * tanh(A@X + bias) ----------------
// 512-thread blocks = 8 independent waves (one __syncthreads total, after A staging).
// A (128x256 bf16, 64KB) lives in LDS with XOR-swizzled 16B chunks -> conflict-spread
// ds_read_b128 fragment reads on the lgkmcnt counter, fully decoupled from the
// vmcnt B-stream. Each wave owns a 32-wide s strip; its two 16-col MFMA n-tiles are
// the EVEN/ODD columns, so B loads are float2 covering full 128B lines. One-step
// register prefetch (fp32 tmp -> bf16 cur at use). acc in AGPRs; no spills at
// launch_bounds(512,4).
__global__ __launch_bounds__(512, 4) void attn_main(
    const float* __restrict__ sta, const float* __restrict__ dyn,
    const unsigned short* __restrict__ Abf, const float* __restrict__ bias,
    const float* __restrict__ v, float* __restrict__ scores) {
  __shared__ unsigned short LA[128 * 256];   // 64 KB, swizzled

  const int tid  = threadIdx.x;
  const int l    = tid & 63;
  const int quad = l >> 4;
  const int n16  = l & 15;
  const int gw   = (blockIdx.x << 3) + (tid >> 6);  // global wave id
  const int b    = gw >> 8;
  const int tile = gw & 255;
  const int s0   = tile << 5;

  // ---- stage A: global (bf16) -> LDS, 16B chunks, phys_chunk = ck ^ (m & 7) ----
  #pragma unroll
  for (int j = 0; j < 8; ++j) {
    int gc = (j << 9) + tid;            // 0..4095 chunk id; m = gc>>5, ck = gc&31
    int m = gc >> 5, ck = gc & 31;
    bf8 val = *(const bf8*)(Abf + ((size_t)gc << 3));
    *(bf8*)&LA[m * 256 + ((ck ^ (m & 7)) << 3)] = val;
  }
  __syncthreads();

  const size_t base = ((size_t)b << 20) + (size_t)(quad << 3) * SS + s0 + (n16 << 1);
  const float* p0 = sta + base;          // rows quad*8.., chunk 0 (k 0..127)
  const float* p1 = dyn + base;          // chunk 1 (k 128..255)

  f4 acc[8][2];
  #pragma unroll
  for (int mt = 0; mt < 8; ++mt) {
    acc[mt][0] = (f4){0.f, 0.f, 0.f, 0.f};
    acc[mt][1] = (f4){0.f, 0.f, 0.f, 0.f};
  }

  f2v tmp[8];
  bf8 cur0, cur1;

  auto issueB = [&](int step) {
    const float* tp = (step < 4 ? p0 : p1) + ((size_t)((step & 3) << 5)) * SS;
    #pragma unroll
    for (int j = 0; j < 8; ++j)
      tmp[j] = *(const f2v*)(tp + (size_t)j * SS);  // full 128B-line segments
  };
  auto conv = [&]() {
    #pragma unroll
    for (int j = 0; j < 8; ++j) {
      cur0[j] = (short)f2bf(tmp[j].x);   // even cols -> tile 0
      cur1[j] = (short)f2bf(tmp[j].y);   // odd cols  -> tile 1
    }
  };

  const int swz = n16 & 7;               // == (m & 7) for every mt since m = 16*mt + n16
  issueB(0);
  conv();
  #pragma unroll
  for (int step = 0; step < 8; ++step) {
    if (step < 7) issueB(step + 1);      // HBM loads in flight across this step's MFMAs
    const int koff = (((step << 2) + quad) ^ swz) << 3;   // swizzled k-chunk offset (elems)
    #pragma unroll
    for (int mt = 0; mt < 8; ++mt) {
      bf8 af = *(const bf8*)&LA[(((mt << 4) + n16) << 8) + koff];  // ds_read_b128
      acc[mt][0] = __builtin_amdgcn_mfma_f32_16x16x32_bf16(af, cur0, acc[mt][0], 0, 0, 0);
      acc[mt][1] = __builtin_amdgcn_mfma_f32_16x16x32_bf16(af, cur1, acc[mt][1], 0, 0, 0);
    }
    if (step < 7) conv();                // waits only on vmcnt for this wave's B stream
  }

  // epilogue: z = acc + bias[h]; part += v[h]*tanh(z); reduce over h across quads
  float part[2] = {0.f, 0.f};
  #pragma unroll
  for (int mt = 0; mt < 8; ++mt) {
    #pragma unroll
    for (int r = 0; r < 4; ++r) {
      const int h = mt * 16 + quad * 4 + r;   // C/D row = quad*4 + reg
      const float bv = bias[(b << 7) + h];
      const float vv = v[h];
      part[0] += vv * tanhf(acc[mt][0][r] + bv);
      part[1] += vv * tanhf(acc[mt][1][r] + bv);
    }
  }
  part[0] += __shfl_xor(part[0], 16, 64);
  part[0] += __shfl_xor(part[0], 32, 64);
  part[1] += __shfl_xor(part[1], 16, 64);
  part[1] += __shfl_xor(part[1], 32, 64);
  if (quad == 0) {
    float2 o = make_float2(part[0], part[1]);  // even col s0+2*n16, odd col +1
    *(float2*)(scores + ((size_t)b << 13) + s0 + (n16 << 1)) = o;
  }
}

// ---------------- softmax over s, in-place on d_out ----------------
__global__ __launch_bounds__(1024) void softmax_kernel(float* __restrict__ out) {
  const int b = blockIdx.x;
  const int tid = threadIdx.x;
  float* row = out + ((size_t)b << 13);
  float4 x0 = ((const float4*)row)[tid];
  float4 x1 = ((const float4*)row)[tid + 1024];
  float lmax = fmaxf(fmaxf(fmaxf(x0.x, x0.y), fmaxf(x0.z, x0.w)),
                     fmaxf(fmaxf(x1.x, x1.y), fmaxf(x1.z, x1.w)));
  __shared__ float red[17];
  #pragma unroll
  for (int o = 32; o >= 1; o >>= 1) lmax = fmaxf(lmax, __shfl_xor(lmax, o, 64));
  if ((tid & 63) == 0) red[tid >> 6] = lmax;
  __syncthreads();
  if (tid < 64) {
    float m = (tid < 16) ? red[tid] : -3.0e38f;
    #pragma unroll
    for (int o = 8; o >= 1; o >>= 1) m = fmaxf(m, __shfl_xor(m, o, 64));
    if (tid == 0) red[16] = m;
  }
  __syncthreads();
  const float gmax = red[16];
  float e[8];
  e[0] = expf(x0.x - gmax); e[1] = expf(x0.y - gmax);
  e[2] = expf(x0.z - gmax); e[3] = expf(x0.w - gmax);
  e[4] = expf(x1.x - gmax); e[5] = expf(x1.y - gmax);
  e[6] = expf(x1.z - gmax); e[7] = expf(x1.w - gmax);
  float ls = e[0] + e[1] + e[2] + e[3] + e[4] + e[5] + e[6] + e[7];
  #pragma unroll
  for (int o = 32; o >= 1; o >>= 1) ls += __shfl_xor(ls, o, 64);
  __syncthreads();   // gmax consumed; safe to reuse red
  if ((tid & 63) == 0) red[tid >> 6] = ls;
  __syncthreads();
  if (tid < 64) {
    float m = (tid < 16) ? red[tid] : 0.f;
    #pragma unroll
    for (int o = 8; o >= 1; o >>= 1) m += __shfl_xor(m, o, 64);
    if (tid == 0) red[16] = m;
  }
  __syncthreads();
  const float inv = 1.0f / red[16];
  float4 o0 = make_float4(e[0] * inv, e[1] * inv, e[2] * inv, e[3] * inv);
  float4 o1 = make_float4(e[4] * inv, e[5] * inv, e[6] * inv, e[7] * inv);
  ((float4*)row)[tid] = o0;
  ((float4*)row)[tid + 1024] = o1;
}

extern "C" void kernel_launch(void* const* d_in, const int* in_sizes, int n_in,
                              void* d_out, int out_size, void* d_ws, size_t ws_size,
                              hipStream_t stream) {
  const float* sta = (const float*)d_in[0];   // (32,128,8192)
  const float* dyn = (const float*)d_in[1];   // (32,128,8192)
  const float* dec = (const float*)d_in[2];   // (32,128)
  const float* v   = (const float*)d_in[3];   // (128)
  const float* W   = (const float*)d_in[4];   // (128,384)

  unsigned short* Abf = (unsigned short*)d_ws;             // 64 KB
  float* bias = (float*)((char*)d_ws + 128 * 256 * 2);     // 16 KB
  float* scores = (float*)d_out;                           // 1 MB, softmaxed in place

  prep_kernel<<<BB, 256, 0, stream>>>(W, dec, Abf, bias);
  attn_main<<<BB * (SS / 32) / 8, 512, 0, stream>>>(sta, dyn, Abf, bias, v, scores);
  softmax_kernel<<<BB, 1024, 0, stream>>>(scores);
}

// Round 5
// 331.150 us; speedup vs baseline: 1.3123x; 1.0910x over previous
//
#include <hip/hip_runtime.h>
#include <math.h>

#define BB 32
#define HH 128
#define SS 8192

typedef __attribute__((ext_vector_type(8))) short bf8;
typedef __attribute__((ext_vector_type(4))) float f4;

static __device__ __forceinline__ unsigned short f2bf(float x) {
  union { float f; unsigned int u; } c; c.f = x;
  unsigned int r = c.u + 0x7FFFu + ((c.u >> 16) & 1u);  // RNE
  return (unsigned short)(r >> 16);
}

// ---------------- prep: bias[b][h] = W[h, 256:384] . dec[b]; Abf = bf16(W[:,0:256]) ----------------
__global__ __launch_bounds__(256) void prep_kernel(
    const float* __restrict__ W, const float* __restrict__ dec,
    unsigned short* __restrict__ Abf, float* __restrict__ bias) {
  const int b = blockIdx.x;
  const int tid = threadIdx.x;
  if (tid < HH) {
    const float* wr = W + (size_t)tid * 384 + 256;
    const float* db = dec + (size_t)b * HH;
    float acc = 0.f;
    #pragma unroll 8
    for (int j = 0; j < HH; ++j) acc += wr[j] * db[j];
    bias[b * HH + tid] = acc;
  }
  if (b == 0) {
    for (int idx = tid; idx < HH * 256; idx += 256) {
      int h = idx >> 8, k = idx & 255;
      Abf[idx] = f2bf(W[h * 384 + k]);
    }
  }
}

// ---------------- main: scores[b][s] = sum_h v[h] * tanh(A@X + bias) ----------------
// 512-thread blocks = 8 independent waves; one __syncthreads (after A staging).
// A (128x256 bf16, 64KB) in LDS, XOR-swizzled 16B chunks; fragment reads are
// ds_read_b128 on lgkmcnt, decoupled from the vmcnt B-stream. Each wave owns a
// 16-wide s strip -> acc is only 32 regs (8 m-tiles x 4), so at launch_bounds(512,4)
// (128 regs/wave, unified VGPR+AGPR) there are ~30 regs of slack: NO spills, and
// LDS allows 2 blocks/CU = 16 waves/CU. B loads: per-lane dword, 4x64B segments
// per instr; adjacent waves cover the complementary line halves.
__global__ __launch_bounds__(512, 4) void attn_main(
    const float* __restrict__ sta, const float* __restrict__ dyn,
    const unsigned short* __restrict__ Abf, const float* __restrict__ bias,
    const float* __restrict__ v, float* __restrict__ scores) {
  __shared__ unsigned short LA[128 * 256];   // 64 KB, swizzled

  const int tid  = threadIdx.x;
  const int l    = tid & 63;
  const int quad = l >> 4;
  const int n16  = l & 15;
  const int gw   = (blockIdx.x << 3) + (tid >> 6);  // global wave id
  const int b    = gw >> 9;
  const int tile = gw & 511;               // 512 tiles of 16 columns
  const int s0   = tile << 4;

  // ---- stage A: global (bf16) -> LDS, 16B chunks, phys_chunk = ck ^ (m & 7) ----
  #pragma unroll
  for (int j = 0; j < 8; ++j) {
    int gc = (j << 9) + tid;            // 0..4095 chunk id; m = gc>>5, ck = gc&31
    int m = gc >> 5, ck = gc & 31;
    bf8 val = *(const bf8*)(Abf + ((size_t)gc << 3));
    *(bf8*)&LA[m * 256 + ((ck ^ (m & 7)) << 3)] = val;
  }
  __syncthreads();

  const size_t base = ((size_t)b << 20) + (size_t)(quad << 3) * SS + s0 + n16;
  const float* p0 = sta + base;          // rows quad*8.., chunk 0 (k 0..127)
  const float* p1 = dyn + base;          // chunk 1 (k 128..255)

  f4 acc[8];
  #pragma unroll
  for (int mt = 0; mt < 8; ++mt) acc[mt] = (f4){0.f, 0.f, 0.f, 0.f};

  float tmp[8];
  bf8 cur;

  auto issueB = [&](int step) {
    const float* tp = (step < 4 ? p0 : p1) + ((size_t)((step & 3) << 5)) * SS;
    #pragma unroll
    for (int j = 0; j < 8; ++j)
      tmp[j] = tp[(size_t)j * SS];       // 4 x 64B segments per instr
  };
  auto conv = [&]() {
    #pragma unroll
    for (int j = 0; j < 8; ++j) cur[j] = (short)f2bf(tmp[j]);
  };

  const int swz = n16 & 7;               // == (m & 7) for every mt since m = 16*mt + n16
  issueB(0);
  conv();
  #pragma unroll
  for (int step = 0; step < 8; ++step) {
    if (step < 7) issueB(step + 1);      // HBM loads in flight across this step's MFMAs
    const int koff = (((step << 2) + quad) ^ swz) << 3;   // swizzled k-chunk offset (elems)
    #pragma unroll
    for (int mt = 0; mt < 8; ++mt) {
      bf8 af = *(const bf8*)&LA[(((mt << 4) + n16) << 8) + koff];  // ds_read_b128
      acc[mt] = __builtin_amdgcn_mfma_f32_16x16x32_bf16(af, cur, acc[mt], 0, 0, 0);
    }
    if (step < 7) conv();                // waits only on this wave's vmcnt B stream
  }

  // epilogue: z = acc + bias[h]; part += v[h]*tanh(z); reduce over h across quads
  float part = 0.f;
  #pragma unroll
  for (int mt = 0; mt < 8; ++mt) {
    #pragma unroll
    for (int r = 0; r < 4; ++r) {
      const int h = mt * 16 + quad * 4 + r;   // C/D row = quad*4 + reg
      part += v[h] * tanhf(acc[mt][r] + bias[(b << 7) + h]);
    }
  }
  part += __shfl_xor(part, 16, 64);
  part += __shfl_xor(part, 32, 64);
  if (quad == 0)
    scores[((size_t)b << 13) + s0 + n16] = part;
}

// ---------------- softmax over s, in-place on d_out ----------------
__global__ __launch_bounds__(1024) void softmax_kernel(float* __restrict__ out) {
  const int b = blockIdx.x;
  const int tid = threadIdx.x;
  float* row = out + ((size_t)b << 13);
  float4 x0 = ((const float4*)row)[tid];
  float4 x1 = ((const float4*)row)[tid + 1024];
  float lmax = fmaxf(fmaxf(fmaxf(x0.x, x0.y), fmaxf(x0.z, x0.w)),
                     fmaxf(fmaxf(x1.x, x1.y), fmaxf(x1.z, x1.w)));
  __shared__ float red[17];
  #pragma unroll
  for (int o = 32; o >= 1; o >>= 1) lmax = fmaxf(lmax, __shfl_xor(lmax, o, 64));
  if ((tid & 63) == 0) red[tid >> 6] = lmax;
  __syncthreads();
  if (tid < 64) {
    float m = (tid < 16) ? red[tid] : -3.0e38f;
    #pragma unroll
    for (int o = 8; o >= 1; o >>= 1) m = fmaxf(m, __shfl_xor(m, o, 64));
    if (tid == 0) red[16] = m;
  }
  __syncthreads();
  const float gmax = red[16];
  float e[8];
  e[0] = expf(x0.x - gmax); e[1] = expf(x0.y - gmax);
  e[2] = expf(x0.z - gmax); e[3] = expf(x0.w - gmax);
  e[4] = expf(x1.x - gmax); e[5] = expf(x1.y - gmax);
  e[6] = expf(x1.z - gmax); e[7] = expf(x1.w - gmax);
  float ls = e[0] + e[1] + e[2] + e[3] + e[4] + e[5] + e[6] + e[7];
  #pragma unroll
  for (int o = 32; o >= 1; o >>= 1) ls += __shfl_xor(ls, o, 64);
  __syncthreads();   // gmax consumed; safe to reuse red
  if ((tid & 63) == 0) red[tid >> 6] = ls;
  __syncthreads();
  if (tid < 64) {
    float m = (tid < 16) ? red[tid] : 0.f;
    #pragma unroll
    for (int o = 8; o >= 1; o >>= 1) m += __shfl_xor(m, o, 64);
    if (tid == 0) red[16] = m;
  }
  __syncthreads();
  const float inv = 1.0f / red[16];
  float4 o0 = make_float4(e[0] * inv, e[1] * inv, e[2] * inv, e[3] * inv);
  float4 o1 = make_float4(e[4] * inv, e[5] * inv, e[6] * inv, e[7] * inv);
  ((float4*)row)[tid] = o0;
  ((float4*)row)[tid + 1024] = o1;
}

extern "C" void kernel_launch(void* const* d_in, const int* in_sizes, int n_in,
                              void* d_out, int out_size, void* d_ws, size_t ws_size,
                              hipStream_t stream) {
  const float* sta = (const float*)d_in[0];   // (32,128,8192)
  const float* dyn = (const float*)d_in[1];   // (32,128,8192)
  const float* dec = (const float*)d_in[2];   // (32,128)
  const float* v   = (const float*)d_in[3];   // (128)
  const float* W   = (const float*)d_in[4];   // (128,384)

  unsigned short* Abf = (unsigned short*)d_ws;             // 64 KB
  float* bias = (float*)((char*)d_ws + 128 * 256 * 2);     // 16 KB
  float* scores = (float*)d_out;                           // 1 MB, softmaxed in place

  prep_kernel<<<BB, 256, 0, stream>>>(W, dec, Abf, bias);
  attn_main<<<BB * (SS / 16) / 8, 512, 0, stream>>>(sta, dyn, Abf, bias, v, scores);
  softmax_kernel<<<BB, 1024, 0, stream>>>(scores);
}